// Round 1
// 1327.294 us; speedup vs baseline: 1.1313x; 1.1313x over previous
//
#include <hip/hip_runtime.h>
#include <hip/hip_bf16.h>
#include <hip/hip_fp16.h>
#include <math.h>

#define N_NODES 65536
#define N_GRAPH 256
#define P_NODES 256
#define N_EDGES 1048576
#define AF 92
#define BF 41
#define DIM 64
#define HID 128
#define NLAYER 3
#define CE 16
#define TS 4
#define BN_EPS 1e-5f
#define EPW 32        // edges per block (one wave) in k_edge4
#define PSTRIDE 33    // padded edge-dim stride of LDS panels (conflict fix)

typedef _Float16 half8 __attribute__((ext_vector_type(8)));
typedef float floatx4 __attribute__((ext_vector_type(4)));

// fast softplus: native v_exp/v_log, abs err ~1e-7 (budget 2e-2)
__device__ __forceinline__ float softplus_f(float x) {
    return fmaxf(x, 0.0f) + __logf(1.0f + __expf(-fabsf(x)));
}

// ---------------------------------------------------------------- initial h
// block=64: one block's x-rows = 64*368B = 23KB -> fits 32KB L1 (128 was 47KB)
__global__ __launch_bounds__(64) void k_h0(
    const float* __restrict__ x, const float* __restrict__ charge,
    const float* __restrict__ chW, const float* __restrict__ chb,
    const float* __restrict__ atomW, const float* __restrict__ atomb,
    const int* __restrict__ batch, float* __restrict__ h)
{
    const int n = blockIdx.x * 64 + threadIdx.x;
    float acc[DIM];
#pragma unroll
    for (int j = 0; j < DIM; ++j) acc[j] = atomb[j];
    const float* xr = x + (size_t)n * AF;
    for (int k2 = 0; k2 < AF; k2 += 2) {
        float2 a = *(const float2*)(xr + k2);
        {
            const float* w = atomW + (size_t)k2 * DIM;
#pragma unroll
            for (int j = 0; j < DIM; ++j) acc[j] = fmaf(w[j], a.x, acc[j]);
        }
        {
            const float* w = atomW + (size_t)(k2 + 1) * DIM;
#pragma unroll
            for (int j = 0; j < DIM; ++j) acc[j] = fmaf(w[j], a.y, acc[j]);
        }
    }
    const float cg = charge[batch[n]];
#pragma unroll
    for (int k = 0; k < CE; ++k) {
        float av = fmaf(cg, chW[k], chb[k]);
        const float* w = atomW + (size_t)(AF + k) * DIM;
#pragma unroll
        for (int j = 0; j < DIM; ++j) acc[j] = fmaf(w[j], av, acc[j]);
    }
    float* hp = h + (size_t)n * DIM;
#pragma unroll
    for (int j = 0; j < DIM; j += 4)
        *(float4*)(hp + j) = make_float4(acc[j], acc[j+1], acc[j+2], acc[j+3]);
}

// ---------------------------------------------------------------- CSR build
__global__ __launch_bounds__(256) void k_hist(const int* __restrict__ ecol,
                                              int* __restrict__ cnt)
{
    int t = blockIdx.x * 256 + threadIdx.x;
    atomicAdd(&cnt[ecol[t]], 1);
}

__global__ __launch_bounds__(256) void k_scan(const int* __restrict__ cnt,
                                              int* __restrict__ starts)
{
    __shared__ int ps[256];
    const int t = threadIdx.x;
    int s = 0;
    for (int i = 0; i < 256; ++i) s += cnt[t * 256 + i];
    ps[t] = s;
    __syncthreads();
    for (int off = 1; off < 256; off <<= 1) {
        int v = (t >= off) ? ps[t - off] : 0;
        __syncthreads();
        ps[t] += v;
        __syncthreads();
    }
    int run = ps[t] - s;
    for (int i = 0; i < 256; ++i) {
        starts[t * 256 + i] = run;
        run += cnt[t * 256 + i];
    }
    if (t == 255) starts[N_NODES] = run;
}

__global__ __launch_bounds__(256) void k_scatter(const int* __restrict__ ecol,
                                                 int* __restrict__ cur,
                                                 int* __restrict__ perm,
                                                 int* __restrict__ ipos)
{
    int t = blockIdx.x * 256 + threadIdx.x;
    int pos = atomicAdd(&cur[ecol[t]], 1);
    perm[pos] = t;
    ipos[t] = pos;
}

// --------------------------- all weight fragments in one kernel (fp16 B-frag)
// per-layer region: euW1 12288 | euW2 4096 | nuW1 8192 | nuW2 4096 halves
__global__ __launch_bounds__(256) void k_wprep_all(
    const float* __restrict__ euW1, const float* __restrict__ euW2,
    const float* __restrict__ nuW1, const float* __restrict__ nuW2,
    __half* __restrict__ out)
{
    const int idx = blockIdx.x * 256 + threadIdx.x;   // grid = 3*28672 threads
    const int layer = idx / 28672;
    int off = idx - layer * 28672;
    const float* W;
    if (off < 12288)        { W = euW1 + (size_t)layer * 192 * DIM; }
    else if (off < 16384)   { W = euW2 + (size_t)layer * DIM * DIM; off -= 12288; }
    else if (off < 24576)   { W = nuW1 + (size_t)layer * 128 * DIM; off -= 16384; }
    else                    { W = nuW2 + (size_t)layer * DIM * DIM; off -= 24576; }
    int j    = off & 7;
    int lane = (off >> 3) & 63;
    int f    = off >> 9;
    int ntile = f & 3;
    int kIter = f >> 2;
    int k = kIter * 32 + ((lane >> 4) & 3) * 8 + j;
    int n = ntile * 16 + (lane & 15);
    out[idx] = __float2half(W[k * 64 + n]);
}

// bondW [41x64] -> fp16 B-fragments for one K=64 panel (zero-padded k>=41).
// 8 frags x 64 lanes x 8 halves = 4096 halves (8KB).
__global__ __launch_bounds__(256) void k_wprep_bond(
    const float* __restrict__ bondW, __half* __restrict__ out)
{
    const int idx = blockIdx.x * 256 + threadIdx.x;   // 4096 threads
    int j    = idx & 7;
    int lane = (idx >> 3) & 63;
    int f    = idx >> 9;
    int ntile = f & 3;
    int kIter = f >> 2;
    int k = kIter * 32 + ((lane >> 4) & 3) * 8 + j;
    int n = ntile * 16 + (lane & 15);
    out[idx] = (k < BF) ? __float2half(bondW[k * 64 + n]) : __float2half(0.0f);
}

// ---------------------------------------------------------------- MFMA edge
__device__ __forceinline__ void init_acc(floatx4 acc[2][4],
                                         const float* __restrict__ b, int mrow)
{
#pragma unroll
    for (int n = 0; n < 4; ++n) {
        float bv = b[n * 16 + mrow];
        floatx4 f = {bv, bv, bv, bv};
        acc[0][n] = f;
        acc[1][n] = f;
    }
}

__device__ __forceinline__ void gemm_panel(floatx4 acc[2][4],
                                           const _Float16* __restrict__ P,
                                           const __half* __restrict__ Wf,
                                           int fragBase, int quad,
                                           int mrow, int lane)
{
    const _Float16* Wh = (const _Float16*)Wf;
#pragma unroll
    for (int ki = 0; ki < 2; ++ki) {
        const _Float16* pa = P + (size_t)(((ki * 4 + quad) * PSTRIDE + mrow) * 8);
        half8 a0 = *(const half8*)pa;
        half8 a1 = *(const half8*)(pa + 16 * 8);
#pragma unroll
        for (int n = 0; n < 4; ++n) {
            half8 b = *(const half8*)(Wh +
                ((size_t)(fragBase + ki * 4 + n) * 64 + lane) * 8);
            acc[0][n] = __builtin_amdgcn_mfma_f32_16x16x32_f16(a0, b, acc[0][n], 0, 0, 0);
            acc[1][n] = __builtin_amdgcn_mfma_f32_16x16x32_f16(a1, b, acc[1][n], 0, 0, 0);
        }
    }
}

__device__ __forceinline__ void cstore_panel(const floatx4 acc[2][4],
                                             _Float16* __restrict__ P,
                                             int quad, int mrow, bool sp)
{
#pragma unroll
    for (int t = 0; t < 2; ++t)
#pragma unroll
        for (int n = 0; n < 4; ++n)
#pragma unroll
            for (int r = 0; r < 4; ++r) {
                int edge = t * 16 + quad * 4 + r;
                int d = n * 16 + mrow;
                float v = acc[t][n][r];
                if (sp) v = softplus_f(v);
                P[((d >> 3) * PSTRIDE + edge) * 8 + (d & 7)] = (_Float16)v;
            }
}

__device__ __forceinline__ void rows_to_global(const _Float16* __restrict__ P,
                                               __half* __restrict__ dst,
                                               int e0, int lane)
{
#pragma unroll
    for (int i = 0; i < 4; ++i) {
        int idx = i * 64 + lane;
        int eL = idx >> 3;
        int c  = idx & 7;
        half8 v = *(const half8*)&P[(c * PSTRIDE + eL) * 8];
        *(half8*)((_Float16*)dst + (size_t)(e0 + eL) * 64 + c * 8) = v;
    }
}

__device__ __forceinline__ void stage_h(const float* __restrict__ hrow,
                                        _Float16* __restrict__ P,
                                        int sEdge, int sSeg)
{
    const float* hp = hrow + sSeg * 32;
#pragma unroll
    for (int i = 0; i < 4; ++i) {
        float4 v0 = *(const float4*)(hp + i * 8);
        float4 v1 = *(const float4*)(hp + i * 8 + 4);
        half8 hv;
        hv[0] = (_Float16)v0.x; hv[1] = (_Float16)v0.y;
        hv[2] = (_Float16)v0.z; hv[3] = (_Float16)v0.w;
        hv[4] = (_Float16)v1.x; hv[5] = (_Float16)v1.y;
        hv[6] = (_Float16)v1.z; hv[7] = (_Float16)v1.w;
        *(half8*)&P[((sSeg * 4 + i) * PSTRIDE + sEdge) * 8] = hv;
    }
}

// ---- initial e as MFMA GEMM: eT[slot] = eattr[E,41] @ bondW[41,64] + bondb.
// One wave / 32 edges. Coalesced float2 reads of the contiguous 5248B eattr
// span, magic-div by 41 to place each element into the fp16 K=64 LDS panel
// (zero-padded), 16 MFMAs, scattered 128B-row writeout via ipos.
__device__ __forceinline__ void stage_e2(_Float16* __restrict__ P,
                                         int id2, float2 v)
{
    int idx = id2 * 2;
    int e = (idx * 51151) >> 21;          // floor(idx/41), exact for idx<2^15
    int k = idx - e * 41;
    P[((k >> 3) * PSTRIDE + e) * 8 + (k & 7)] = (_Float16)v.x;
    idx++;
    e = (idx * 51151) >> 21;
    k = idx - e * 41;
    P[((k >> 3) * PSTRIDE + e) * 8 + (k & 7)] = (_Float16)v.y;
}

__global__ __launch_bounds__(64) void k_e0m(
    const float* __restrict__ eattr, const __half* __restrict__ Wb,
    const float* __restrict__ bondb, const int* __restrict__ ipos,
    __half* __restrict__ eT)
{
    __shared__ __align__(16) _Float16 P0[8 * PSTRIDE * 8];
    __shared__ int slot[32];
    const int lane = threadIdx.x;
    const int quad = lane >> 4;
    const int mrow = lane & 15;
    const int e0   = blockIdx.x * 32;

    if (lane < 32) slot[lane] = ipos[e0 + lane];

    // zero the panel (covers k=41..63 padding; real data overwrites below)
    {
        half8 z = {};
#pragma unroll
        for (int i = 0; i < 4; ++i) ((half8*)P0)[i * 64 + lane] = z;
        if (lane < 8) ((half8*)P0)[256 + lane] = z;   // 264 total
    }
    __syncthreads();

    // stage 32 edges x 41 feats (1312 floats = 656 float2, contiguous)
    const float* src = eattr + (size_t)e0 * BF;
#pragma unroll
    for (int i = 0; i < 10; ++i) {
        const int id2 = i * 64 + lane;
        float2 v = *(const float2*)(src + id2 * 2);
        stage_e2(P0, id2, v);
    }
    if (lane < 16) {
        const int id2 = 640 + lane;
        float2 v = *(const float2*)(src + id2 * 2);
        stage_e2(P0, id2, v);
    }
    __syncthreads();

    floatx4 acc[2][4];
    init_acc(acc, bondb, mrow);
    gemm_panel(acc, P0, Wb, 0, quad, mrow, lane);
    __syncthreads();
    cstore_panel(acc, P0, quad, mrow, false);
    __syncthreads();

    // scattered writeout: 8 consecutive lanes cover one 128B row
#pragma unroll
    for (int i = 0; i < 4; ++i) {
        int idx = i * 64 + lane;
        int eL = idx >> 3;
        int c  = idx & 7;
        half8 v = *(const half8*)&P0[(c * PSTRIDE + eL) * 8];
        *(half8*)((_Float16*)eT + (size_t)slot[eL] * DIM + c * 8) = v;
    }
}

// Single-wave block: 64 threads, 32 edges (2 M-tiles x 4 N-tiles per GEMM).
// Workgroup == wave -> compiler elides s_barrier (no vmcnt(0) drains).
// Edges processed in CSR (dst-sorted) order via perm; eT row prefetched into
// registers at kernel start so the load rides through GEMM1's MFMA latency.
__global__ __launch_bounds__(64) void k_edge4(
    const float* __restrict__ h, __half* __restrict__ eT,
    const __half* __restrict__ Wf,
    const float* __restrict__ eub1, const float* __restrict__ eub2,
    const float* __restrict__ nub1, const float* __restrict__ nub2,
    const int* __restrict__ erow, const int* __restrict__ ecol,
    const int* __restrict__ perm,
    __half* __restrict__ m)
{
    __shared__ __align__(16) _Float16 P0[8 * PSTRIDE * 8];
    __shared__ __align__(16) _Float16 P1[8 * PSTRIDE * 8];
    const int lane = threadIdx.x;
    const int quad = lane >> 4;
    const int mrow = lane & 15;
    const int e0   = blockIdx.x * EPW;
    const int sEdge = lane >> 1;
    const int sSeg  = lane & 1;

    floatx4 acc[2][4];

    // prefetch this wave's e rows (consumed after GEMM1-hd)
    half8 epre[4];
    {
        const _Float16* ep = (const _Float16*)(eT + (size_t)(e0 + sEdge) * DIM) + sSeg * 32;
#pragma unroll
        for (int i = 0; i < 4; ++i) epre[i] = *(const half8*)(ep + i * 8);
    }

    const int ed = perm[e0 + sEdge];
    stage_h(h + (size_t)erow[ed] * DIM, P0, sEdge, sSeg);   // hs
    stage_h(h + (size_t)ecol[ed] * DIM, P1, sEdge, sSeg);   // hd
    __syncthreads();

    // ---- GEMM1: t1 = [hs|hd|e] @ euW1 + eub1
    init_acc(acc, eub1, mrow);
    gemm_panel(acc, P0, Wf, 0, quad, mrow, lane);    // hs (k 0..63)
    gemm_panel(acc, P1, Wf, 8, quad, mrow, lane);    // hd (k 64..127)
    __syncthreads();
    {   // stage prefetched e -> P1 (overwrite hd)
#pragma unroll
        for (int i = 0; i < 4; ++i)
            *(half8*)&P1[((sSeg * 4 + i) * PSTRIDE + sEdge) * 8] = epre[i];
    }
    __syncthreads();
    gemm_panel(acc, P1, Wf, 16, quad, mrow, lane);   // e (k 128..191)
    __syncthreads();
    cstore_panel(acc, P1, quad, mrow, true);         // sp(t1) -> P1
    __syncthreads();

    // ---- GEMM2: e_new = sp(t1) @ euW2 + eub2
    init_acc(acc, eub2, mrow);
    gemm_panel(acc, P1, Wf, 24, quad, mrow, lane);
    __syncthreads();
    cstore_panel(acc, P1, quad, mrow, false);        // e_new -> P1
    __syncthreads();
    rows_to_global(P1, eT, e0, lane);                // persist e_new

    // ---- GEMM3: t2 = [hs|e_new] @ nuW1 + nub1
    init_acc(acc, nub1, mrow);
    gemm_panel(acc, P0, Wf, 32, quad, mrow, lane);   // hs
    gemm_panel(acc, P1, Wf, 40, quad, mrow, lane);   // e_new
    __syncthreads();
    cstore_panel(acc, P0, quad, mrow, true);         // sp(t2) -> P0
    __syncthreads();

    // ---- GEMM4: m = sp(t2) @ nuW2 + nub2
    init_acc(acc, nub2, mrow);
    gemm_panel(acc, P0, Wf, 48, quad, mrow, lane);
    __syncthreads();
    cstore_panel(acc, P1, quad, mrow, false);        // m -> P1
    __syncthreads();
    rows_to_global(P1, m, e0, lane);
}

// -------------------- segment sum over contiguous (dst-sorted) m rows
__global__ __launch_bounds__(256) void k_agg(
    const __half2* __restrict__ m2, const int* __restrict__ starts,
    float* __restrict__ hn)
{
    const int w = threadIdx.x >> 6;
    const int lane = threadIdx.x & 63;
    const int n = blockIdx.x * 4 + w;
    const int s = starts[n], e = starts[n + 1];
    const int r = lane >> 5, d2 = lane & 31;
    float ax = 0.f, ay = 0.f;
    for (int i = s + r; i < e; i += 2) {
        float2 f = __half22float2(m2[(size_t)i * 32 + d2]);
        ax += f.x; ay += f.y;
    }
    ax += __shfl(ax, lane ^ 32, 64);
    ay += __shfl(ay, lane ^ 32, 64);
    if (r == 0) *(float2*)(hn + (size_t)n * DIM + d2 * 2) = make_float2(ax, ay);
}

// ---------------------------------------------------------------- BN + update
__global__ __launch_bounds__(256) void k_bnstats(const float* __restrict__ hn,
                                                 float* __restrict__ stats)
{
    const int j = threadIdx.x & 63;
    const int sub = threadIdx.x >> 6;
    const int r0 = blockIdx.x * 256;
    float s = 0.f, qq = 0.f;
    for (int i = 0; i < 64; ++i) {
        float v = hn[(size_t)(r0 + i * 4 + sub) * DIM + j];
        s += v;
        qq = fmaf(v, v, qq);
    }
    __shared__ float ls[256], lq[256];
    ls[threadIdx.x] = s; lq[threadIdx.x] = qq;
    __syncthreads();
    if (threadIdx.x < 128) {
        ls[threadIdx.x] += ls[threadIdx.x + 128];
        lq[threadIdx.x] += lq[threadIdx.x + 128];
    }
    __syncthreads();
    if (threadIdx.x < 64) {
        atomicAdd(&stats[j],      ls[threadIdx.x] + ls[threadIdx.x + 64]);
        atomicAdd(&stats[64 + j], lq[threadIdx.x] + lq[threadIdx.x + 64]);
    }
}

__global__ __launch_bounds__(256) void k_hupd(
    const float* __restrict__ hn, float* __restrict__ h,
    const float* __restrict__ stats, const float* __restrict__ gamma,
    const float* __restrict__ beta)
{
    const size_t idx = (size_t)blockIdx.x * 256 + threadIdx.x;
    const int j = (int)(idx & 63);
    const float inv_n = 1.0f / (float)N_NODES;
    float mu  = stats[j] * inv_n;
    float var = stats[64 + j] * inv_n - mu * mu;
    float sc  = gamma[j] * rsqrtf(var + BN_EPS);
    float v   = (hn[idx] - mu) * sc + beta[j];
    h[idx] += softplus_f(v);
}

// ---------------------------------------------------------------- pool + MLP
__global__ __launch_bounds__(64) void k_pool(const float* __restrict__ h,
                                             const int* __restrict__ tsi,
                                             float* __restrict__ gr)
{
    const int g = blockIdx.x, j = threadIdx.x;
    float s = 0.f;
#pragma unroll
    for (int t = 0; t < TS; ++t) {
        int p = tsi[g * TS + t];
        s += h[(size_t)(g * P_NODES + p) * DIM + j];
    }
    gr[g * DIM + j] = s * (1.0f / TS);
}

__global__ __launch_bounds__(128) void k_pred(const float* __restrict__ gr,
    const float* __restrict__ W1, const float* __restrict__ b1,
    const float* __restrict__ W2, const float* __restrict__ b2,
    const float* __restrict__ W3, const float* __restrict__ b3,
    float* __restrict__ out)
{
    const int g = blockIdx.x, j = threadIdx.x;
    __shared__ float zin[DIM], z1[HID], red[HID];
    if (j < DIM) zin[j] = gr[g * DIM + j];
    __syncthreads();
    float a = b1[j];
    for (int k = 0; k < DIM; ++k) a = fmaf(zin[k], W1[k * HID + j], a);
    z1[j] = softplus_f(a);
    __syncthreads();
    float a2 = b2[j];
    for (int k = 0; k < HID; ++k) a2 = fmaf(z1[k], W2[k * HID + j], a2);
    red[j] = softplus_f(a2) * W3[j];
    __syncthreads();
    for (int s = 64; s > 0; s >>= 1) {
        if (j < s) red[j] += red[j + s];
        __syncthreads();
    }
    if (j == 0) out[g] = red[0] + b3[0];
}

extern "C" void kernel_launch(void* const* d_in, const int* in_sizes, int n_in,
                              void* d_out, int out_size, void* d_ws, size_t ws_size,
                              hipStream_t stream)
{
    const float* x      = (const float*)d_in[0];
    const float* eattr  = (const float*)d_in[1];
    const float* charge = (const float*)d_in[2];
    const float* chW    = (const float*)d_in[3];
    const float* chb    = (const float*)d_in[4];
    const float* atomW  = (const float*)d_in[5];
    const float* atomb  = (const float*)d_in[6];
    const float* bondW  = (const float*)d_in[7];
    const float* bondb  = (const float*)d_in[8];
    const float* nuW1   = (const float*)d_in[9];
    const float* nub1   = (const float*)d_in[10];
    const float* nuW2   = (const float*)d_in[11];
    const float* nub2   = (const float*)d_in[12];
    const float* euW1   = (const float*)d_in[13];
    const float* eub1   = (const float*)d_in[14];
    const float* euW2   = (const float*)d_in[15];
    const float* eub2   = (const float*)d_in[16];
    const float* gamma  = (const float*)d_in[17];
    const float* beta   = (const float*)d_in[18];
    const float* pW1    = (const float*)d_in[19];
    const float* pb1    = (const float*)d_in[20];
    const float* pW2    = (const float*)d_in[21];
    const float* pb2    = (const float*)d_in[22];
    const float* pW3    = (const float*)d_in[23];
    const float* pb3    = (const float*)d_in[24];
    const int*   eidx   = (const int*)d_in[25];
    const int*   batch  = (const int*)d_in[26];
    const int*   tsi    = (const int*)d_in[27];
    const int* erow = eidx;
    const int* ecol = eidx + N_EDGES;

    // workspace (~296 MB):
    // h@0 16M | hn@16M 16M (ipos aliases first 4M: consumed by k_e0m before
    // k_agg's first write) | stats@32M | gr@32M+64K | counts@33M 256K |
    // starts@33M+256K | cur@33M+768K | Wfrag@34M 172K | Wbond@34M+256K 8K |
    // perm@35M 4M | eT@40M 128M | m@168M 128M
    char* ws = (char*)d_ws;
    float*  h      = (float*)(ws);
    float*  hn     = (float*)(ws + ((size_t)16 << 20));
    int*    ipos   = (int*)  (ws + ((size_t)16 << 20));   // aliases hn (safe)
    float*  stats  = (float*)(ws + ((size_t)32 << 20));
    float*  gr     = (float*)(ws + ((size_t)32 << 20) + (64 << 10));
    int*    counts = (int*)  (ws + ((size_t)33 << 20));
    int*    starts = (int*)  (ws + ((size_t)33 << 20) + (256 << 10));
    int*    cur    = (int*)  (ws + ((size_t)33 << 20) + (768 << 10));
    __half* Wfrag  = (__half*)(ws + ((size_t)34 << 20));
    __half* Wbond  = (__half*)(ws + ((size_t)34 << 20) + (256 << 10));
    int*    perm   = (int*)  (ws + ((size_t)35 << 20));
    __half* eT     = (__half*)(ws + ((size_t)40 << 20));
    __half* m      = (__half*)(ws + ((size_t)168 << 20));

    // ---- CSR build (edge order for ALL layers = dst-sorted via perm/ipos)
    hipMemsetAsync(counts, 0, N_NODES * sizeof(int), stream);
    k_hist<<<N_EDGES / 256, 256, 0, stream>>>(ecol, counts);
    k_scan<<<1, 256, 0, stream>>>(counts, starts);
    hipMemcpyAsync(cur, starts, N_NODES * sizeof(int),
                   hipMemcpyDeviceToDevice, stream);
    k_scatter<<<N_EDGES / 256, 256, 0, stream>>>(ecol, cur, perm, ipos);

    // ---- weight fragment pre-pack (all layers/matrices + bondW)
    k_wprep_all<<<(3 * 28672) / 256, 256, 0, stream>>>(euW1, euW2, nuW1, nuW2, Wfrag);
    k_wprep_bond<<<16, 256, 0, stream>>>(bondW, Wbond);

    // ---- embeddings
    k_h0<<<N_NODES / 64, 64, 0, stream>>>(x, charge, chW, chb, atomW, atomb, batch, h);
    k_e0m<<<N_EDGES / 32, 64, 0, stream>>>(eattr, Wbond, bondb, ipos, eT);

    const size_t LW = 28672;
    for (int i = 0; i < NLAYER; ++i) {
        hipMemsetAsync(stats, 0, 128 * sizeof(float), stream);
        k_edge4<<<N_EDGES / EPW, 64, 0, stream>>>(h, eT, Wfrag + i * LW,
            eub1 + i * DIM, eub2 + i * DIM, nub1 + i * DIM, nub2 + i * DIM,
            erow, ecol, perm, m);
        k_agg<<<N_NODES / 4, 256, 0, stream>>>((const __half2*)m, starts, hn);
        k_bnstats<<<N_NODES / 256, 256, 0, stream>>>(hn, stats);
        k_hupd<<<(N_NODES * DIM) / 256, 256, 0, stream>>>(hn, h, stats,
            gamma + i * DIM, beta + i * DIM);
    }

    k_pool<<<N_GRAPH, 64, 0, stream>>>(h, tsi, gr);
    k_pred<<<N_GRAPH, HID, 0, stream>>>(gr, pW1, pb1, pW2, pb2, pW3, pb3, (float*)d_out);
}

// Round 2
// 1278.109 us; speedup vs baseline: 1.1749x; 1.0385x over previous
//
#include <hip/hip_runtime.h>
#include <hip/hip_bf16.h>
#include <hip/hip_fp16.h>
#include <math.h>

#define N_NODES 65536
#define N_GRAPH 256
#define P_NODES 256
#define N_EDGES 1048576
#define AF 92
#define BF 41
#define DIM 64
#define HID 128
#define NLAYER 3
#define CE 16
#define TS 4
#define BN_EPS 1e-5f
#define EPW 32        // edges per block (one wave) in k_edge4
#define PSTRIDE 33    // padded edge-dim stride of LDS panels (conflict fix)

typedef _Float16 half8 __attribute__((ext_vector_type(8)));
typedef _Float16 half4_t __attribute__((ext_vector_type(4)));
typedef float floatx4 __attribute__((ext_vector_type(4)));

// fast softplus: native v_exp/v_log, abs err ~1e-7 (budget 2e-2)
__device__ __forceinline__ float softplus_f(float x) {
    return fmaxf(x, 0.0f) + __logf(1.0f + __expf(-fabsf(x)));
}

// ---------------------------------------------------------------- initial h
// writes fp32 master h AND fp16 mirror h16 (consumed by k_edge4)
__global__ __launch_bounds__(64) void k_h0(
    const float* __restrict__ x, const float* __restrict__ charge,
    const float* __restrict__ chW, const float* __restrict__ chb,
    const float* __restrict__ atomW, const float* __restrict__ atomb,
    const int* __restrict__ batch, float* __restrict__ h,
    __half* __restrict__ h16)
{
    const int n = blockIdx.x * 64 + threadIdx.x;
    float acc[DIM];
#pragma unroll
    for (int j = 0; j < DIM; ++j) acc[j] = atomb[j];
    const float* xr = x + (size_t)n * AF;
    for (int k2 = 0; k2 < AF; k2 += 2) {
        float2 a = *(const float2*)(xr + k2);
        {
            const float* w = atomW + (size_t)k2 * DIM;
#pragma unroll
            for (int j = 0; j < DIM; ++j) acc[j] = fmaf(w[j], a.x, acc[j]);
        }
        {
            const float* w = atomW + (size_t)(k2 + 1) * DIM;
#pragma unroll
            for (int j = 0; j < DIM; ++j) acc[j] = fmaf(w[j], a.y, acc[j]);
        }
    }
    const float cg = charge[batch[n]];
#pragma unroll
    for (int k = 0; k < CE; ++k) {
        float av = fmaf(cg, chW[k], chb[k]);
        const float* w = atomW + (size_t)(AF + k) * DIM;
#pragma unroll
        for (int j = 0; j < DIM; ++j) acc[j] = fmaf(w[j], av, acc[j]);
    }
    float* hp = h + (size_t)n * DIM;
    _Float16* hq = (_Float16*)h16 + (size_t)n * DIM;
#pragma unroll
    for (int j = 0; j < DIM; j += 4)
        *(float4*)(hp + j) = make_float4(acc[j], acc[j+1], acc[j+2], acc[j+3]);
#pragma unroll
    for (int j = 0; j < DIM; j += 8) {
        half8 hv;
#pragma unroll
        for (int u = 0; u < 8; ++u) hv[u] = (_Float16)acc[j + u];
        *(half8*)(hq + j) = hv;
    }
}

// ---------------------------------------------------------------- CSR build
__global__ __launch_bounds__(256) void k_hist(const int* __restrict__ ecol,
                                              int* __restrict__ cnt)
{
    int t = blockIdx.x * 256 + threadIdx.x;
    atomicAdd(&cnt[ecol[t]], 1);
}

// hierarchical scan: blocksums -> scan blocksums -> per-block scan + offset
__global__ __launch_bounds__(256) void k_blksum(const int* __restrict__ cnt,
                                                int* __restrict__ bs)
{
    __shared__ int red[256];
    red[threadIdx.x] = cnt[blockIdx.x * 256 + threadIdx.x];
    __syncthreads();
    for (int o = 128; o > 0; o >>= 1) {
        if (threadIdx.x < o) red[threadIdx.x] += red[threadIdx.x + o];
        __syncthreads();
    }
    if (threadIdx.x == 0) bs[blockIdx.x] = red[0];
}

__global__ __launch_bounds__(256) void k_scanb(const int* __restrict__ bs,
                                               int* __restrict__ bo)
{
    __shared__ int ps[256];
    const int t = threadIdx.x;
    int v = bs[t];
    ps[t] = v;
    __syncthreads();
    for (int off = 1; off < 256; off <<= 1) {
        int u = (t >= off) ? ps[t - off] : 0;
        __syncthreads();
        ps[t] += u;
        __syncthreads();
    }
    bo[t] = ps[t] - v;   // exclusive
}

__global__ __launch_bounds__(256) void k_scan3(const int* __restrict__ cnt,
                                               const int* __restrict__ bo,
                                               int* __restrict__ starts)
{
    __shared__ int ps[256];
    const int b = blockIdx.x, t = threadIdx.x;
    int v = cnt[b * 256 + t];
    ps[t] = v;
    __syncthreads();
    for (int off = 1; off < 256; off <<= 1) {
        int u = (t >= off) ? ps[t - off] : 0;
        __syncthreads();
        ps[t] += u;
        __syncthreads();
    }
    starts[b * 256 + t] = bo[b] + ps[t] - v;
    if (b == 255 && t == 255) starts[N_NODES] = bo[255] + ps[255];
}

__global__ __launch_bounds__(256) void k_scatter(const int* __restrict__ ecol,
                                                 int* __restrict__ cur,
                                                 int* __restrict__ perm,
                                                 int* __restrict__ ipos)
{
    int t = blockIdx.x * 256 + threadIdx.x;
    int pos = atomicAdd(&cur[ecol[t]], 1);
    perm[pos] = t;
    ipos[t] = pos;
}

// --------------------------- all weight fragments in one kernel (fp16 B-frag)
// per-layer region: euW1 12288 | euW2 4096 | nuW1 8192 | nuW2 4096 halves
__global__ __launch_bounds__(256) void k_wprep_all(
    const float* __restrict__ euW1, const float* __restrict__ euW2,
    const float* __restrict__ nuW1, const float* __restrict__ nuW2,
    __half* __restrict__ out)
{
    const int idx = blockIdx.x * 256 + threadIdx.x;   // grid = 3*28672 threads
    const int layer = idx / 28672;
    int off = idx - layer * 28672;
    const float* W;
    if (off < 12288)        { W = euW1 + (size_t)layer * 192 * DIM; }
    else if (off < 16384)   { W = euW2 + (size_t)layer * DIM * DIM; off -= 12288; }
    else if (off < 24576)   { W = nuW1 + (size_t)layer * 128 * DIM; off -= 16384; }
    else                    { W = nuW2 + (size_t)layer * DIM * DIM; off -= 24576; }
    int j    = off & 7;
    int lane = (off >> 3) & 63;
    int f    = off >> 9;
    int ntile = f & 3;
    int kIter = f >> 2;
    int k = kIter * 32 + ((lane >> 4) & 3) * 8 + j;
    int n = ntile * 16 + (lane & 15);
    out[idx] = __float2half(W[k * 64 + n]);
}

// bondW [41x64] -> fp16 B-fragments for one K=64 panel (zero-padded k>=41).
__global__ __launch_bounds__(256) void k_wprep_bond(
    const float* __restrict__ bondW, __half* __restrict__ out)
{
    const int idx = blockIdx.x * 256 + threadIdx.x;   // 4096 threads
    int j    = idx & 7;
    int lane = (idx >> 3) & 63;
    int f    = idx >> 9;
    int ntile = f & 3;
    int kIter = f >> 2;
    int k = kIter * 32 + ((lane >> 4) & 3) * 8 + j;
    int n = ntile * 16 + (lane & 15);
    out[idx] = (k < BF) ? __float2half(bondW[k * 64 + n]) : __float2half(0.0f);
}

// fused weight: W' = euW2 @ nuW1_bot  [64x64], b' = eub2 @ nuW1_bot + nub1.
// Lets GEMM3 consume sp(t1) directly (no GEMM2->GEMM3 dependency).
__global__ __launch_bounds__(64) void k_wfuse(
    const float* __restrict__ euW2, const float* __restrict__ nuW1,
    const float* __restrict__ eub2, const float* __restrict__ nub1,
    float* __restrict__ WfuF32, float* __restrict__ bfu)
{
    const int L = blockIdx.x, j = threadIdx.x;
    const float* W2  = euW2 + (size_t)L * DIM * DIM;             // [k][l]
    const float* N1b = nuW1 + (size_t)L * 128 * DIM + 64 * DIM;  // [l][j]
    float acc[64];
#pragma unroll
    for (int k = 0; k < 64; ++k) acc[k] = 0.f;
    for (int l = 0; l < 64; ++l) {
        float nv = N1b[l * 64 + j];
#pragma unroll
        for (int k = 0; k < 64; ++k) acc[k] = fmaf(W2[k * 64 + l], nv, acc[k]);
    }
    float* outW = WfuF32 + (size_t)L * 4096;
    for (int k = 0; k < 64; ++k) outW[k * 64 + j] = acc[k];
    float b = nub1[L * 64 + j];
    for (int l = 0; l < 64; ++l) b = fmaf(eub2[L * 64 + l], N1b[l * 64 + j], b);
    bfu[L * 64 + j] = b;
}

__global__ __launch_bounds__(256) void k_wprep_fuse(
    const float* __restrict__ WfuF32, __half* __restrict__ out)
{
    const int idx = blockIdx.x * 256 + threadIdx.x;   // 3*4096 threads
    const int layer = idx >> 12;
    int off = idx & 4095;
    int j    = off & 7;
    int lane = (off >> 3) & 63;
    int f    = off >> 9;
    int ntile = f & 3;
    int kIter = f >> 2;
    int k = kIter * 32 + ((lane >> 4) & 3) * 8 + j;
    int n = ntile * 16 + (lane & 15);
    out[idx] = __float2half(WfuF32[(size_t)layer * 4096 + k * 64 + n]);
}

// ---------------------------------------------------------------- MFMA edge
__device__ __forceinline__ void init_acc(floatx4 acc[2][4],
                                         const float* __restrict__ b, int mrow)
{
#pragma unroll
    for (int n = 0; n < 4; ++n) {
        float bv = b[n * 16 + mrow];
        floatx4 f = {bv, bv, bv, bv};
        acc[0][n] = f;
        acc[1][n] = f;
    }
}

__device__ __forceinline__ void gemm_panel(floatx4 acc[2][4],
                                           const _Float16* __restrict__ P,
                                           const __half* __restrict__ Wf,
                                           int fragBase, int quad,
                                           int mrow, int lane)
{
    const _Float16* Wh = (const _Float16*)Wf;
#pragma unroll
    for (int ki = 0; ki < 2; ++ki) {
        const _Float16* pa = P + (size_t)(((ki * 4 + quad) * PSTRIDE + mrow) * 8);
        half8 a0 = *(const half8*)pa;
        half8 a1 = *(const half8*)(pa + 16 * 8);
#pragma unroll
        for (int n = 0; n < 4; ++n) {
            half8 b = *(const half8*)(Wh +
                ((size_t)(fragBase + ki * 4 + n) * 64 + lane) * 8);
            acc[0][n] = __builtin_amdgcn_mfma_f32_16x16x32_f16(a0, b, acc[0][n], 0, 0, 0);
            acc[1][n] = __builtin_amdgcn_mfma_f32_16x16x32_f16(a1, b, acc[1][n], 0, 0, 0);
        }
    }
}

__device__ __forceinline__ void cstore_panel(const floatx4 acc[2][4],
                                             _Float16* __restrict__ P,
                                             int quad, int mrow, bool sp)
{
#pragma unroll
    for (int t = 0; t < 2; ++t)
#pragma unroll
        for (int n = 0; n < 4; ++n)
#pragma unroll
            for (int r = 0; r < 4; ++r) {
                int edge = t * 16 + quad * 4 + r;
                int d = n * 16 + mrow;
                float v = acc[t][n][r];
                if (sp) v = softplus_f(v);
                P[((d >> 3) * PSTRIDE + edge) * 8 + (d & 7)] = (_Float16)v;
            }
}

__device__ __forceinline__ void rows_to_global(const _Float16* __restrict__ P,
                                               __half* __restrict__ dst,
                                               int e0, int lane)
{
#pragma unroll
    for (int i = 0; i < 4; ++i) {
        int idx = i * 64 + lane;
        int eL = idx >> 3;
        int c  = idx & 7;
        half8 v = *(const half8*)&P[(c * PSTRIDE + eL) * 8];
        *(half8*)((_Float16*)dst + (size_t)(e0 + eL) * 64 + c * 8) = v;
    }
}

// native fragment-layout store of m: per (t,n) a coalesced 512B chunk.
// halfidx within 32-edge block: (((t*4+n)*4+quad)*16+mrow)*4 + r
// where edge = t*16+quad*4+r, dim = n*16+mrow. Block = 2048 halves (4KB).
__device__ __forceinline__ void store_m_native(const floatx4 acc[2][4],
        __half* __restrict__ m, int blk, int quad, int mrow)
{
    _Float16* base = (_Float16*)m + (size_t)blk * 2048;
#pragma unroll
    for (int t = 0; t < 2; ++t)
#pragma unroll
        for (int n = 0; n < 4; ++n) {
            half4_t hv;
            hv[0] = (_Float16)acc[t][n][0];
            hv[1] = (_Float16)acc[t][n][1];
            hv[2] = (_Float16)acc[t][n][2];
            hv[3] = (_Float16)acc[t][n][3];
            *(half4_t*)(base + ((((t * 4 + n) * 4 + quad) * 16 + mrow) * 4)) = hv;
        }
}

__device__ __forceinline__ void stage_h16(const __half* __restrict__ hrow,
                                          _Float16* __restrict__ P,
                                          int sEdge, int sSeg)
{
    const _Float16* hp = (const _Float16*)hrow + sSeg * 32;
#pragma unroll
    for (int i = 0; i < 4; ++i) {
        half8 hv = *(const half8*)(hp + i * 8);
        *(half8*)&P[((sSeg * 4 + i) * PSTRIDE + sEdge) * 8] = hv;
    }
}

// Single-wave block: 64 threads, 32 edges. GEMM3 uses fused W' so it reads
// sp(t1) directly; GEMM2 runs on a second accumulator concurrently; m is
// stored straight from the accumulator in native fragment layout.
__global__ __launch_bounds__(64, 4) void k_edge4(
    const __half* __restrict__ h16, __half* __restrict__ eT,
    const __half* __restrict__ Wf, const __half* __restrict__ Wfu,
    const float* __restrict__ eub1, const float* __restrict__ eub2,
    const float* __restrict__ bfu,  const float* __restrict__ nub2,
    const int* __restrict__ erow, const int* __restrict__ ecol,
    const int* __restrict__ perm,
    __half* __restrict__ m)
{
    __shared__ __align__(16) _Float16 P0[8 * PSTRIDE * 8];
    __shared__ __align__(16) _Float16 P1[8 * PSTRIDE * 8];
    const int lane = threadIdx.x;
    const int quad = lane >> 4;
    const int mrow = lane & 15;
    const int e0   = blockIdx.x * EPW;
    const int sEdge = lane >> 1;
    const int sSeg  = lane & 1;

    floatx4 acc[2][4], acc2[2][4];

    // prefetch this wave's e rows (consumed after GEMM1-hd)
    half8 epre[4];
    {
        const _Float16* ep = (const _Float16*)(eT + (size_t)(e0 + sEdge) * DIM) + sSeg * 32;
#pragma unroll
        for (int i = 0; i < 4; ++i) epre[i] = *(const half8*)(ep + i * 8);
    }

    const int ed = perm[e0 + sEdge];
    stage_h16(h16 + (size_t)erow[ed] * DIM, P0, sEdge, sSeg);   // hs
    stage_h16(h16 + (size_t)ecol[ed] * DIM, P1, sEdge, sSeg);   // hd
    __syncthreads();

    // ---- GEMM1: t1 = [hs|hd|e] @ euW1 + eub1
    init_acc(acc, eub1, mrow);
    gemm_panel(acc, P0, Wf, 0, quad, mrow, lane);    // hs (k 0..63)
    gemm_panel(acc, P1, Wf, 8, quad, mrow, lane);    // hd (k 64..127)
    __syncthreads();
    {   // stage prefetched e -> P1 (overwrite hd)
#pragma unroll
        for (int i = 0; i < 4; ++i)
            *(half8*)&P1[((sSeg * 4 + i) * PSTRIDE + sEdge) * 8] = epre[i];
    }
    __syncthreads();
    gemm_panel(acc, P1, Wf, 16, quad, mrow, lane);   // e (k 128..191)
    __syncthreads();
    cstore_panel(acc, P1, quad, mrow, true);         // sp(t1) -> P1
    __syncthreads();

    // ---- GEMM3 (fused): t2 = hs@nuW1_top + sp(t1)@W' + b'
    init_acc(acc, bfu, mrow);
    gemm_panel(acc, P0, Wf, 32, quad, mrow, lane);   // hs
    gemm_panel(acc, P1, Wfu, 0, quad, mrow, lane);   // sp(t1) @ W'
    // ---- GEMM2 (independent): e_new = sp(t1) @ euW2 + eub2
    init_acc(acc2, eub2, mrow);
    gemm_panel(acc2, P1, Wf, 24, quad, mrow, lane);
    __syncthreads();
    cstore_panel(acc, P0, quad, mrow, true);         // sp(t2) -> P0 (hs dead)
    __syncthreads();

    // ---- GEMM4: m = sp(t2) @ nuW2 + nub2
    init_acc(acc, nub2, mrow);
    gemm_panel(acc, P0, Wf, 48, quad, mrow, lane);
    __syncthreads();
    cstore_panel(acc2, P1, quad, mrow, false);       // e_new -> P1
    __syncthreads();
    rows_to_global(P1, eT, e0, lane);                // persist e_new
    store_m_native(acc, m, blockIdx.x, quad, mrow);  // m direct from acc
}

// -------------------- segment sum over native-layout m (4 edges per load)
__global__ __launch_bounds__(256) void k_agg(
    const __half* __restrict__ m, const int* __restrict__ starts,
    __half* __restrict__ hn)
{
    const int w = threadIdx.x >> 6;
    const int lane = threadIdx.x & 63;
    const int n = blockIdx.x * 4 + w;
    const int s = starts[n], e = starts[n + 1];
    const int nn = lane >> 4, mrow = lane & 15;
    float acc = 0.f;
    for (int g = s & ~3; g < e; g += 4) {
        int blk = g >> 5;
        int off = g & 31;
        int t = off >> 4, quad = (off >> 2) & 3;
        half4_t v = *(const half4_t*)((const _Float16*)m + (size_t)blk * 2048
                     + (((t * 4 + nn) * 4 + quad) * 16 + mrow) * 4);
        float f0 = (float)v[0], f1 = (float)v[1];
        float f2 = (float)v[2], f3 = (float)v[3];
        if (g >= s && g + 3 < e) {                 // wave-uniform branch
            acc += (f0 + f1) + (f2 + f3);
        } else {
            if (g     >= s && g     < e) acc += f0;
            if (g + 1 >= s && g + 1 < e) acc += f1;
            if (g + 2 >= s && g + 2 < e) acc += f2;
            if (g + 3 >= s && g + 3 < e) acc += f3;
        }
    }
    hn[(size_t)n * DIM + lane] = (__half)acc;
}

// ---------------------------------------------------------------- BN + update
__global__ __launch_bounds__(256) void k_bnstats(const __half* __restrict__ hn,
                                                 float* __restrict__ stats)
{
    const int j = threadIdx.x & 63;
    const int sub = threadIdx.x >> 6;
    const int r0 = blockIdx.x * 256;
    float s = 0.f, qq = 0.f;
    for (int i = 0; i < 64; ++i) {
        float v = (float)hn[(size_t)(r0 + i * 4 + sub) * DIM + j];
        s += v;
        qq = fmaf(v, v, qq);
    }
    __shared__ float ls[256], lq[256];
    ls[threadIdx.x] = s; lq[threadIdx.x] = qq;
    __syncthreads();
    if (threadIdx.x < 128) {
        ls[threadIdx.x] += ls[threadIdx.x + 128];
        lq[threadIdx.x] += lq[threadIdx.x + 128];
    }
    __syncthreads();
    if (threadIdx.x < 64) {
        atomicAdd(&stats[j],      ls[threadIdx.x] + ls[threadIdx.x + 64]);
        atomicAdd(&stats[64 + j], lq[threadIdx.x] + lq[threadIdx.x + 64]);
    }
}

__global__ __launch_bounds__(256) void k_hupd(
    const __half* __restrict__ hn, float* __restrict__ h,
    __half* __restrict__ h16,
    const float* __restrict__ stats, const float* __restrict__ gamma,
    const float* __restrict__ beta)
{
    const size_t idx = (size_t)blockIdx.x * 256 + threadIdx.x;
    const int j = (int)(idx & 63);
    const float inv_n = 1.0f / (float)N_NODES;
    float mu  = stats[j] * inv_n;
    float var = stats[64 + j] * inv_n - mu * mu;
    float sc  = gamma[j] * rsqrtf(var + BN_EPS);
    float v   = ((float)hn[idx] - mu) * sc + beta[j];
    float nh  = h[idx] + softplus_f(v);
    h[idx] = nh;
    h16[idx] = (__half)nh;
}

// ---- initial e as MFMA GEMM (unchanged from prior round)
__device__ __forceinline__ void stage_e2(_Float16* __restrict__ P,
                                         int id2, float2 v)
{
    int idx = id2 * 2;
    int e = (idx * 51151) >> 21;          // floor(idx/41), exact for idx<2^15
    int k = idx - e * 41;
    P[((k >> 3) * PSTRIDE + e) * 8 + (k & 7)] = (_Float16)v.x;
    idx++;
    e = (idx * 51151) >> 21;
    k = idx - e * 41;
    P[((k >> 3) * PSTRIDE + e) * 8 + (k & 7)] = (_Float16)v.y;
}

__global__ __launch_bounds__(64) void k_e0m(
    const float* __restrict__ eattr, const __half* __restrict__ Wb,
    const float* __restrict__ bondb, const int* __restrict__ ipos,
    __half* __restrict__ eT)
{
    __shared__ __align__(16) _Float16 P0[8 * PSTRIDE * 8];
    __shared__ int slot[32];
    const int lane = threadIdx.x;
    const int quad = lane >> 4;
    const int mrow = lane & 15;
    const int e0   = blockIdx.x * 32;

    if (lane < 32) slot[lane] = ipos[e0 + lane];

    {
        half8 z = {};
#pragma unroll
        for (int i = 0; i < 4; ++i) ((half8*)P0)[i * 64 + lane] = z;
        if (lane < 8) ((half8*)P0)[256 + lane] = z;
    }
    __syncthreads();

    const float* src = eattr + (size_t)e0 * BF;
#pragma unroll
    for (int i = 0; i < 10; ++i) {
        const int id2 = i * 64 + lane;
        float2 v = *(const float2*)(src + id2 * 2);
        stage_e2(P0, id2, v);
    }
    if (lane < 16) {
        const int id2 = 640 + lane;
        float2 v = *(const float2*)(src + id2 * 2);
        stage_e2(P0, id2, v);
    }
    __syncthreads();

    floatx4 acc[2][4];
    init_acc(acc, bondb, mrow);
    gemm_panel(acc, P0, Wb, 0, quad, mrow, lane);
    __syncthreads();
    cstore_panel(acc, P0, quad, mrow, false);
    __syncthreads();

#pragma unroll
    for (int i = 0; i < 4; ++i) {
        int idx = i * 64 + lane;
        int eL = idx >> 3;
        int c  = idx & 7;
        half8 v = *(const half8*)&P0[(c * PSTRIDE + eL) * 8];
        *(half8*)((_Float16*)eT + (size_t)slot[eL] * DIM + c * 8) = v;
    }
}

// ---------------------------------------------------------------- pool + MLP
__global__ __launch_bounds__(64) void k_pool(const float* __restrict__ h,
                                             const int* __restrict__ tsi,
                                             float* __restrict__ gr)
{
    const int g = blockIdx.x, j = threadIdx.x;
    float s = 0.f;
#pragma unroll
    for (int t = 0; t < TS; ++t) {
        int p = tsi[g * TS + t];
        s += h[(size_t)(g * P_NODES + p) * DIM + j];
    }
    gr[g * DIM + j] = s * (1.0f / TS);
}

__global__ __launch_bounds__(128) void k_pred(const float* __restrict__ gr,
    const float* __restrict__ W1, const float* __restrict__ b1,
    const float* __restrict__ W2, const float* __restrict__ b2,
    const float* __restrict__ W3, const float* __restrict__ b3,
    float* __restrict__ out)
{
    const int g = blockIdx.x, j = threadIdx.x;
    __shared__ float zin[DIM], z1[HID], red[HID];
    if (j < DIM) zin[j] = gr[g * DIM + j];
    __syncthreads();
    float a = b1[j];
    for (int k = 0; k < DIM; ++k) a = fmaf(zin[k], W1[k * HID + j], a);
    z1[j] = softplus_f(a);
    __syncthreads();
    float a2 = b2[j];
    for (int k = 0; k < HID; ++k) a2 = fmaf(z1[k], W2[k * HID + j], a2);
    red[j] = softplus_f(a2) * W3[j];
    __syncthreads();
    for (int s = 64; s > 0; s >>= 1) {
        if (j < s) red[j] += red[j + s];
        __syncthreads();
    }
    if (j == 0) out[g] = red[0] + b3[0];
}

extern "C" void kernel_launch(void* const* d_in, const int* in_sizes, int n_in,
                              void* d_out, int out_size, void* d_ws, size_t ws_size,
                              hipStream_t stream)
{
    const float* x      = (const float*)d_in[0];
    const float* eattr  = (const float*)d_in[1];
    const float* charge = (const float*)d_in[2];
    const float* chW    = (const float*)d_in[3];
    const float* chb    = (const float*)d_in[4];
    const float* atomW  = (const float*)d_in[5];
    const float* atomb  = (const float*)d_in[6];
    const float* bondW  = (const float*)d_in[7];
    const float* bondb  = (const float*)d_in[8];
    const float* nuW1   = (const float*)d_in[9];
    const float* nub1   = (const float*)d_in[10];
    const float* nuW2   = (const float*)d_in[11];
    const float* nub2   = (const float*)d_in[12];
    const float* euW1   = (const float*)d_in[13];
    const float* eub1   = (const float*)d_in[14];
    const float* euW2   = (const float*)d_in[15];
    const float* eub2   = (const float*)d_in[16];
    const float* gamma  = (const float*)d_in[17];
    const float* beta   = (const float*)d_in[18];
    const float* pW1    = (const float*)d_in[19];
    const float* pb1    = (const float*)d_in[20];
    const float* pW2    = (const float*)d_in[21];
    const float* pb2    = (const float*)d_in[22];
    const float* pW3    = (const float*)d_in[23];
    const float* pb3    = (const float*)d_in[24];
    const int*   eidx   = (const int*)d_in[25];
    const int*   batch  = (const int*)d_in[26];
    const int*   tsi    = (const int*)d_in[27];
    const int* erow = eidx;
    const int* ecol = eidx + N_EDGES;

    // workspace (~296 MB):
    // h@0 16M | hn(fp16)@16M 8M (ipos aliases first 4M) | h16@24M 8M |
    // stats@32M | gr@32M+64K | bs@32M+192K | bo@32M+196K |
    // counts@33M | starts@33M+256K | cur@33M+768K |
    // Wfrag@34M 168K | Wbond@34M+256K | Wfu@34M+320K | bfu@34M+384K |
    // WfuF32@34M+448K | perm@35M 4M | eT@40M 128M | m@168M 128M
    char* ws = (char*)d_ws;
    float*  h      = (float*)(ws);
    __half* hn     = (__half*)(ws + ((size_t)16 << 20));
    int*    ipos   = (int*)  (ws + ((size_t)16 << 20));   // aliases hn (safe)
    __half* h16    = (__half*)(ws + ((size_t)24 << 20));
    float*  stats  = (float*)(ws + ((size_t)32 << 20));
    float*  gr     = (float*)(ws + ((size_t)32 << 20) + (64 << 10));
    int*    bs     = (int*)  (ws + ((size_t)32 << 20) + (192 << 10));
    int*    bo     = (int*)  (ws + ((size_t)32 << 20) + (196 << 10));
    int*    counts = (int*)  (ws + ((size_t)33 << 20));
    int*    starts = (int*)  (ws + ((size_t)33 << 20) + (256 << 10));
    int*    cur    = (int*)  (ws + ((size_t)33 << 20) + (768 << 10));
    __half* Wfrag  = (__half*)(ws + ((size_t)34 << 20));
    __half* Wbond  = (__half*)(ws + ((size_t)34 << 20) + (256 << 10));
    __half* Wfu    = (__half*)(ws + ((size_t)34 << 20) + (320 << 10));
    float*  bfu    = (float*)(ws + ((size_t)34 << 20) + (384 << 10));
    float*  WfuF32 = (float*)(ws + ((size_t)34 << 20) + (448 << 10));
    int*    perm   = (int*)  (ws + ((size_t)35 << 20));
    __half* eT     = (__half*)(ws + ((size_t)40 << 20));
    __half* m      = (__half*)(ws + ((size_t)168 << 20));

    // ---- CSR build (edge order for ALL layers = dst-sorted via perm/ipos)
    hipMemsetAsync(counts, 0, N_NODES * sizeof(int), stream);
    k_hist<<<N_EDGES / 256, 256, 0, stream>>>(ecol, counts);
    k_blksum<<<256, 256, 0, stream>>>(counts, bs);
    k_scanb<<<1, 256, 0, stream>>>(bs, bo);
    k_scan3<<<256, 256, 0, stream>>>(counts, bo, starts);
    hipMemcpyAsync(cur, starts, N_NODES * sizeof(int),
                   hipMemcpyDeviceToDevice, stream);
    k_scatter<<<N_EDGES / 256, 256, 0, stream>>>(ecol, cur, perm, ipos);

    // ---- weight fragment pre-pack (all layers/matrices + bond + fused)
    k_wprep_all<<<(3 * 28672) / 256, 256, 0, stream>>>(euW1, euW2, nuW1, nuW2, Wfrag);
    k_wprep_bond<<<16, 256, 0, stream>>>(bondW, Wbond);
    k_wfuse<<<3, 64, 0, stream>>>(euW2, nuW1, eub2, nub1, WfuF32, bfu);
    k_wprep_fuse<<<48, 256, 0, stream>>>(WfuF32, Wfu);

    // ---- embeddings
    k_h0<<<N_NODES / 64, 64, 0, stream>>>(x, charge, chW, chb, atomW, atomb,
                                          batch, h, h16);
    k_e0m<<<N_EDGES / 32, 64, 0, stream>>>(eattr, Wbond, bondb, ipos, eT);

    const size_t LW = 28672;
    for (int i = 0; i < NLAYER; ++i) {
        hipMemsetAsync(stats, 0, 128 * sizeof(float), stream);
        k_edge4<<<N_EDGES / EPW, 64, 0, stream>>>(h16, eT, Wfrag + i * LW,
            Wfu + (size_t)i * 4096,
            eub1 + i * DIM, eub2 + i * DIM, bfu + i * DIM, nub2 + i * DIM,
            erow, ecol, perm, m);
        k_agg<<<N_NODES / 4, 256, 0, stream>>>(m, starts, hn);
        k_bnstats<<<N_NODES / 256, 256, 0, stream>>>(hn, stats);
        k_hupd<<<(N_NODES * DIM) / 256, 256, 0, stream>>>(hn, h, h16, stats,
            gamma + i * DIM, beta + i * DIM);
    }

    k_pool<<<N_GRAPH, 64, 0, stream>>>(h, tsi, gr);
    k_pred<<<N_GRAPH, HID, 0, stream>>>(gr, pW1, pb1, pW2, pb2, pW3, pb3, (float*)d_out);
}